// Round 1
// baseline (305.062 us; speedup 1.0000x reference)
//
#include <hip/hip_runtime.h>
#include <math.h>

// Problem constants (RetinaLoss): B=8, A=76725, C=80, M=20
#define B_CNT 8
#define A_CNT 76725
#define C_CNT 80
#define M_CNT 20

constexpr int XR = (A_CNT + 255) / 256;   // 300 blocks/image for assign
constexpr int XC = 512;                   // blocks/image for focal
constexpr int NG = (A_CNT + 15) / 16;     // anchor groups of 16 (focal)

// ---------------------------------------------------------------------------
// Kernel 1: anchor assignment + smooth-L1 partials
// one thread per anchor
// ---------------------------------------------------------------------------
__global__ __launch_bounds__(256) void assign_kernel(
    const float* __restrict__ anchors,    // [B,A,4]
    const float* __restrict__ reg_heads,  // [B,A,4]
    const float* __restrict__ ann,        // [B,M,5]
    float* __restrict__ cls_out,          // [B,A]
    double* __restrict__ partial_reg,     // [B,XR]
    int* __restrict__ partial_pos)        // [B,XR]
{
    __shared__ float s_ann[M_CNT * 5];
    const int b   = blockIdx.y;
    const int tid = threadIdx.x;
    if (tid < M_CNT * 5) s_ann[tid] = ann[b * M_CNT * 5 + tid];
    __syncthreads();

    const int a = blockIdx.x * 256 + tid;
    double slsum = 0.0;
    int pos = 0;

    if (a < A_CNT) {
        const float4 ab = ((const float4*)anchors)[b * A_CNT + a];
        const float ax1 = ab.x, ay1 = ab.y, ax2 = ab.z, ay2 = ab.w;
        const bool border = (ax1 > 0.0f) && (ay1 > 0.0f) &&
                            (ax2 < 640.0f) && (ay2 < 640.0f);
        const float area_a = (ax2 - ax1) * (ay2 - ay1);

        float best = -INFINITY;
        int   bi   = 0;
        bool  anyv = false;
        #pragma unroll
        for (int m = 0; m < M_CNT; ++m) {
            const float gx1 = s_ann[m * 5 + 0];
            const float gy1 = s_ann[m * 5 + 1];
            const float gx2 = s_ann[m * 5 + 2];
            const float gy2 = s_ann[m * 5 + 3];
            const float gc  = s_ann[m * 5 + 4];
            const bool v = (gc >= 0.0f);
            anyv = anyv || v;
            const float ltx = fmaxf(ax1, gx1), lty = fmaxf(ay1, gy1);
            const float rbx = fminf(ax2, gx2), rby = fminf(ay2, gy2);
            const float wx = fmaxf(rbx - ltx, 0.0f);
            const float wy = fmaxf(rby - lty, 0.0f);
            const float inter = wx * wy;
            const float area_g = (gx2 - gx1) * (gy2 - gy1);
            const float uni = area_a + area_g - inter;
            const float iou = v ? (inter / fmaxf(uni, 1e-6f)) : -1.0f;
            if (iou > best) { best = iou; bi = m; }   // first-max (jnp.argmax)
        }

        float clsv = -1.0f;
        if (anyv) {
            if (best < 0.4f)       clsv = 0.0f;
            else if (best >= 0.5f) clsv = s_ann[bi * 5 + 4] + 1.0f;
        }
        if (!border) clsv = -1.0f;
        cls_out[b * A_CNT + a] = clsv;

        if (clsv > 0.0f) {   // positive anchor -> smooth-L1 term
            pos = 1;
            const float gx1 = s_ann[bi * 5 + 0];
            const float gy1 = s_ann[bi * 5 + 1];
            const float gx2 = s_ann[bi * 5 + 2];
            const float gy2 = s_ann[bi * 5 + 3];
            const float aw = ax2 - ax1, ah = ay2 - ay1;
            const float acx = ax1 + 0.5f * aw, acy = ay1 + 0.5f * ah;
            const float gw = fmaxf(gx2 - gx1, 1.0f);
            const float gh = fmaxf(gy2 - gy1, 1.0f);
            const float gcx = gx1 + 0.5f * gw, gcy = gy1 + 0.5f * gh;
            const float t0 = ((gcx - acx) / aw) / 0.1f;
            const float t1 = ((gcy - acy) / ah) / 0.1f;
            const float t2 = logf(gw / aw) / 0.2f;
            const float t3 = logf(gh / ah) / 0.2f;
            const float4 rh = ((const float4*)reg_heads)[b * A_CNT + a];

            const float BETA = (float)(1.0 / 9.0);
            const float HB   = (float)(0.5 * (1.0 / 9.0));
            auto sl1 = [&](float x) {
                x = fabsf(x);
                return (x >= BETA) ? (x - HB) : (0.5f * x * x / BETA);
            };
            const float s = (sl1(rh.x - t0) + sl1(rh.y - t1) +
                             sl1(rh.z - t2) + sl1(rh.w - t3)) * 0.25f;
            slsum = (double)s;
        }
    }

    // block reduce (4 waves)
    for (int o = 32; o; o >>= 1) {
        slsum += __shfl_down(slsum, o);
        pos   += __shfl_down(pos, o);
    }
    __shared__ double sd[4];
    __shared__ int    si[4];
    const int w = tid >> 6;
    if ((tid & 63) == 0) { sd[w] = slsum; si[w] = pos; }
    __syncthreads();
    if (tid == 0) {
        partial_reg[b * XR + blockIdx.x] = sd[0] + sd[1] + sd[2] + sd[3];
        partial_pos[b * XR + blockIdx.x] = si[0] + si[1] + si[2] + si[3];
    }
}

// ---------------------------------------------------------------------------
// Kernel 2: focal loss. 20 threads x float4 per anchor (80 classes),
// block = 320 threads -> 16 anchors/group, perfectly coalesced reads.
// ---------------------------------------------------------------------------
__global__ __launch_bounds__(320) void focal_kernel(
    const float* __restrict__ cls_heads,  // [B,A,C]
    const float* __restrict__ cls_f,      // [B,A]
    double* __restrict__ partial_cls)     // [B,XC]
{
    const int b   = blockIdx.y;
    const int tid = threadIdx.x;
    const int la  = tid / 20;         // local anchor 0..15
    const int c0  = (tid % 20) * 4;   // class offset

    double acc = 0.0;
    for (int g = blockIdx.x; g < NG; g += XC) {
        const int a = g * 16 + la;
        if (a >= A_CNT) continue;
        const float clsv = cls_f[b * A_CNT + a];
        if (clsv < 0.0f) continue;            // keep-mask: skip entire row
        const int gidx = (int)clsv - 1;       // -1 when clsv==0 -> no match

        const float4 p4 = *((const float4*)(
            cls_heads + ((size_t)b * A_CNT + (size_t)a) * C_CNT + c0));
        const float pp[4] = {p4.x, p4.y, p4.z, p4.w};

        float lacc = 0.0f;
        #pragma unroll
        for (int j = 0; j < 4; ++j) {
            const float p   = fminf(fmaxf(pp[j], 1e-4f), 0.9999f);
            const float omp = 1.0f - p;               // pt for neg branch
            const bool  isgt = (c0 + j) == gidx;
            // focal = af * (1-pt)^2 * (-log(pt_arg)) with one log per element
            const float q  = isgt ? omp : (1.0f - omp);
            const float af = isgt ? 0.25f : 0.75f;
            const float x  = isgt ? p : omp;
            lacc += af * (q * q) * (-__logf(x));
        }
        acc += (double)lacc;
    }

    // block reduce (5 waves)
    for (int o = 32; o; o >>= 1) acc += __shfl_down(acc, o);
    __shared__ double sd[5];
    if ((tid & 63) == 0) sd[tid >> 6] = acc;
    __syncthreads();
    if (tid == 0)
        partial_cls[b * XC + blockIdx.x] = sd[0] + sd[1] + sd[2] + sd[3] + sd[4];
}

// ---------------------------------------------------------------------------
// Kernel 3: final reduction + normalization -> 2 scalars
// ---------------------------------------------------------------------------
__global__ __launch_bounds__(256) void finalize_kernel(
    const double* __restrict__ partial_cls,  // [B,XC]
    const double* __restrict__ partial_reg,  // [B,XR]
    const int* __restrict__ partial_pos,     // [B,XR]
    float* __restrict__ out)
{
    const int tid = threadIdx.x;
    __shared__ double sc[4], sr[4];
    __shared__ int    sp[4];

    double cls_tot = 0.0, reg_tot = 0.0;
    int nv = 0;

    for (int b = 0; b < B_CNT; ++b) {
        double cs = 0.0;
        for (int i = tid; i < XC; i += 256) cs += partial_cls[b * XC + i];
        double rs = 0.0;
        int    ps = 0;
        for (int i = tid; i < XR; i += 256) {
            rs += partial_reg[b * XR + i];
            ps += partial_pos[b * XR + i];
        }
        for (int o = 32; o; o >>= 1) {
            cs += __shfl_down(cs, o);
            rs += __shfl_down(rs, o);
            ps += __shfl_down(ps, o);
        }
        const int w = tid >> 6;
        if ((tid & 63) == 0) { sc[w] = cs; sr[w] = rs; sp[w] = ps; }
        __syncthreads();
        if (tid == 0) {
            const double c = sc[0] + sc[1] + sc[2] + sc[3];
            const double r = sr[0] + sr[1] + sr[2] + sr[3];
            const int    p = sp[0] + sp[1] + sp[2] + sp[3];
            if (p > 0) { cls_tot += c / (double)p; reg_tot += r / (double)p; ++nv; }
        }
        __syncthreads();
    }

    if (tid == 0) {
        const int n = (nv > 0) ? nv : 1;
        out[0] = (float)(cls_tot / (double)n);
        out[1] = (float)(reg_tot / (double)n);
    }
}

// ---------------------------------------------------------------------------
extern "C" void kernel_launch(void* const* d_in, const int* in_sizes, int n_in,
                              void* d_out, int out_size, void* d_ws, size_t ws_size,
                              hipStream_t stream) {
    const float* cls_heads = (const float*)d_in[0];
    const float* reg_heads = (const float*)d_in[1];
    const float* anchors   = (const float*)d_in[2];
    const float* ann       = (const float*)d_in[3];
    float* out = (float*)d_out;

    char* ws = (char*)d_ws;
    double* partial_cls = (double*)ws;                         // 8*512*8 = 32768 B
    double* partial_reg = (double*)(ws + 32768);               // 8*300*8 = 19200 B
    int*    partial_pos = (int*)(ws + 32768 + 19200);          // 8*300*4 =  9600 B
    float*  cls_f       = (float*)(ws + 32768 + 19200 + 9600); // 8*76725*4 B

    assign_kernel<<<dim3(XR, B_CNT), 256, 0, stream>>>(
        anchors, reg_heads, ann, cls_f, partial_reg, partial_pos);
    focal_kernel<<<dim3(XC, B_CNT), 320, 0, stream>>>(
        cls_heads, cls_f, partial_cls);
    finalize_kernel<<<1, 256, 0, stream>>>(
        partial_cls, partial_reg, partial_pos, out);
}

// Round 4
// 290.222 us; speedup vs baseline: 1.0511x; 1.0511x over previous
//
#include <hip/hip_runtime.h>
#include <math.h>

// Problem constants (RetinaLoss): B=8, A=76725, C=80, M=20
#define B_CNT 8
#define A_CNT 76725
#define C_CNT 80
#define M_CNT 20

constexpr int XR = (A_CNT + 255) / 256;   // 300 anchor-chunks of 256 per image

// ---------------------------------------------------------------------------
// Fused kernel: per block = 256 anchors of one image.
// Phase 1: one thread per anchor -> assignment (IoU argmax over 20 GTs),
//          cls label to LDS, smooth-L1 for positives.
// Phase 2: all 256 threads stream the block's 256x80 cls_heads slab as
//          sequential float4s (perfect coalescing), focal loss with one
//          log per element, skipping anchors with cls < 0.
// Block reduce -> per-(image,chunk) partials. No global intermediates.
// ---------------------------------------------------------------------------
__global__ __launch_bounds__(256) void fused_kernel(
    const float* __restrict__ cls_heads,  // [B,A,C]
    const float* __restrict__ reg_heads,  // [B,A,4]
    const float* __restrict__ anchors,    // [B,A,4]
    const float* __restrict__ ann,        // [B,M,5]
    double* __restrict__ partial_cls,     // [B,XR]
    double* __restrict__ partial_reg,     // [B,XR]
    int* __restrict__ partial_pos)        // [B,XR]
{
    __shared__ float s_ann[M_CNT * 5];
    __shared__ float s_cls[256];
    const int b   = blockIdx.y;
    const int tid = threadIdx.x;
    if (tid < M_CNT * 5) s_ann[tid] = ann[b * M_CNT * 5 + tid];
    __syncthreads();

    const int a0 = blockIdx.x * 256;
    const int a  = a0 + tid;

    double slsum = 0.0;
    int    pos   = 0;
    float  clsv  = -1.0f;   // anchors past A_CNT stay "ignore" -> phase 2 skips

    if (a < A_CNT) {
        const float4 ab = ((const float4*)anchors)[b * A_CNT + a];
        const float ax1 = ab.x, ay1 = ab.y, ax2 = ab.z, ay2 = ab.w;
        const bool border = (ax1 > 0.0f) && (ay1 > 0.0f) &&
                            (ax2 < 640.0f) && (ay2 < 640.0f);
        const float area_a = (ax2 - ax1) * (ay2 - ay1);

        float best = -INFINITY;
        int   bi   = 0;
        bool  anyv = false;
        #pragma unroll
        for (int m = 0; m < M_CNT; ++m) {
            const float gx1 = s_ann[m * 5 + 0];
            const float gy1 = s_ann[m * 5 + 1];
            const float gx2 = s_ann[m * 5 + 2];
            const float gy2 = s_ann[m * 5 + 3];
            const float gc  = s_ann[m * 5 + 4];
            const bool v = (gc >= 0.0f);
            anyv = anyv || v;
            const float ltx = fmaxf(ax1, gx1), lty = fmaxf(ay1, gy1);
            const float rbx = fminf(ax2, gx2), rby = fminf(ay2, gy2);
            const float wx = fmaxf(rbx - ltx, 0.0f);
            const float wy = fmaxf(rby - lty, 0.0f);
            const float inter = wx * wy;
            const float area_g = (gx2 - gx1) * (gy2 - gy1);
            const float uni = area_a + area_g - inter;
            const float iou = v ? (inter / fmaxf(uni, 1e-6f)) : -1.0f;
            if (iou > best) { best = iou; bi = m; }   // first-max (jnp.argmax)
        }

        if (anyv) {
            if (best < 0.4f)       clsv = 0.0f;
            else if (best >= 0.5f) clsv = s_ann[bi * 5 + 4] + 1.0f;
            // else stays -1 (ignore)
        }
        if (!border) clsv = -1.0f;

        if (clsv > 0.0f) {   // positive anchor -> smooth-L1 term
            pos = 1;
            const float gx1 = s_ann[bi * 5 + 0];
            const float gy1 = s_ann[bi * 5 + 1];
            const float gx2 = s_ann[bi * 5 + 2];
            const float gy2 = s_ann[bi * 5 + 3];
            const float aw = ax2 - ax1, ah = ay2 - ay1;
            const float acx = ax1 + 0.5f * aw, acy = ay1 + 0.5f * ah;
            const float gw = fmaxf(gx2 - gx1, 1.0f);
            const float gh = fmaxf(gy2 - gy1, 1.0f);
            const float gcx = gx1 + 0.5f * gw, gcy = gy1 + 0.5f * gh;
            const float t0 = ((gcx - acx) / aw) / 0.1f;
            const float t1 = ((gcy - acy) / ah) / 0.1f;
            const float t2 = logf(gw / aw) / 0.2f;
            const float t3 = logf(gh / ah) / 0.2f;
            const float4 rh = ((const float4*)reg_heads)[b * A_CNT + a];

            const float BETA = (float)(1.0 / 9.0);
            const float HB   = (float)(0.5 * (1.0 / 9.0));
            auto sl1 = [&](float x) {
                x = fabsf(x);
                return (x >= BETA) ? (x - HB) : (0.5f * x * x / BETA);
            };
            const float s = (sl1(rh.x - t0) + sl1(rh.y - t1) +
                             sl1(rh.z - t2) + sl1(rh.w - t3)) * 0.25f;
            slsum = (double)s;
        }
    }
    s_cls[tid] = clsv;
    __syncthreads();

    // ---- Phase 2: focal loss over this block's 256x80 slab ----
    // 256 anchors * 20 float4/anchor = 5120 float4s, 20 per thread,
    // index tid + i*256 -> strictly sequential addresses across the block.
    const float* slab = cls_heads + ((size_t)b * A_CNT + (size_t)a0) * C_CNT;
    double acc = 0.0;
    #pragma unroll 4
    for (int i = 0; i < 20; ++i) {
        const int idx = tid + (i << 8);
        const int la  = idx / 20;               // local anchor 0..255
        const int c0  = (idx - la * 20) * 4;    // class offset 0,4,...,76
        const float cv = s_cls[la];
        if (cv < 0.0f) continue;                // keep-mask: skip row
        const int gidx = (int)cv - 1;           // -1 when cv==0 (all-negative)

        const float4 p4 = *((const float4*)(slab + (size_t)la * C_CNT + c0));
        const float pp[4] = {p4.x, p4.y, p4.z, p4.w};

        float lacc = 0.0f;
        #pragma unroll
        for (int j = 0; j < 4; ++j) {
            const float p   = fminf(fmaxf(pp[j], 1e-4f), 0.9999f);
            const float omp = 1.0f - p;
            const bool  isgt = (c0 + j) == gidx;
            // focal = af * (1-pt)^2 * (-log(pt_arg)), one log per element
            const float q  = isgt ? omp : (1.0f - omp);  // (1-pt)
            const float af = isgt ? 0.25f : 0.75f;
            const float x  = isgt ? p : omp;             // log argument
            lacc += af * (q * q) * (-__logf(x));
        }
        acc += (double)lacc;
    }

    // ---- block reduce (4 waves of 64) ----
    for (int o = 32; o; o >>= 1) {
        acc   += __shfl_down(acc, o);
        slsum += __shfl_down(slsum, o);
        pos   += __shfl_down(pos, o);
    }
    __shared__ double sdc[4], sdr[4];
    __shared__ int    sip[4];
    const int w = tid >> 6;
    if ((tid & 63) == 0) { sdc[w] = acc; sdr[w] = slsum; sip[w] = pos; }
    __syncthreads();
    if (tid == 0) {
        partial_cls[b * XR + blockIdx.x] = sdc[0] + sdc[1] + sdc[2] + sdc[3];
        partial_reg[b * XR + blockIdx.x] = sdr[0] + sdr[1] + sdr[2] + sdr[3];
        partial_pos[b * XR + blockIdx.x] = sip[0] + sip[1] + sip[2] + sip[3];
    }
}

// ---------------------------------------------------------------------------
// Finalize: reduce per-chunk partials, normalize, write 2 scalars
// ---------------------------------------------------------------------------
__global__ __launch_bounds__(256) void finalize_kernel(
    const double* __restrict__ partial_cls,  // [B,XR]
    const double* __restrict__ partial_reg,  // [B,XR]
    const int* __restrict__ partial_pos,     // [B,XR]
    float* __restrict__ out)
{
    const int tid = threadIdx.x;
    __shared__ double sc[4], sr[4];
    __shared__ int    sp[4];

    double cls_tot = 0.0, reg_tot = 0.0;
    int nv = 0;

    for (int b = 0; b < B_CNT; ++b) {
        double cs = 0.0, rs = 0.0;
        int    ps = 0;
        for (int i = tid; i < XR; i += 256) {
            cs += partial_cls[b * XR + i];
            rs += partial_reg[b * XR + i];
            ps += partial_pos[b * XR + i];
        }
        for (int o = 32; o; o >>= 1) {
            cs += __shfl_down(cs, o);
            rs += __shfl_down(rs, o);
            ps += __shfl_down(ps, o);
        }
        const int w = tid >> 6;
        if ((tid & 63) == 0) { sc[w] = cs; sr[w] = rs; sp[w] = ps; }
        __syncthreads();
        if (tid == 0) {
            const double c = sc[0] + sc[1] + sc[2] + sc[3];
            const double r = sr[0] + sr[1] + sr[2] + sr[3];
            const int    p = sp[0] + sp[1] + sp[2] + sp[3];
            if (p > 0) { cls_tot += c / (double)p; reg_tot += r / (double)p; ++nv; }
        }
        __syncthreads();
    }

    if (tid == 0) {
        const int n = (nv > 0) ? nv : 1;
        out[0] = (float)(cls_tot / (double)n);
        out[1] = (float)(reg_tot / (double)n);
    }
}

// ---------------------------------------------------------------------------
extern "C" void kernel_launch(void* const* d_in, const int* in_sizes, int n_in,
                              void* d_out, int out_size, void* d_ws, size_t ws_size,
                              hipStream_t stream) {
    const float* cls_heads = (const float*)d_in[0];
    const float* reg_heads = (const float*)d_in[1];
    const float* anchors   = (const float*)d_in[2];
    const float* ann       = (const float*)d_in[3];
    float* out = (float*)d_out;

    char* ws = (char*)d_ws;
    double* partial_cls = (double*)ws;                       // 8*300*8 = 19200 B
    double* partial_reg = (double*)(ws + 19200);             // 19200 B
    int*    partial_pos = (int*)(ws + 38400);                //  9600 B

    fused_kernel<<<dim3(XR, B_CNT), 256, 0, stream>>>(
        cls_heads, reg_heads, anchors, ann,
        partial_cls, partial_reg, partial_pos);
    finalize_kernel<<<1, 256, 0, stream>>>(
        partial_cls, partial_reg, partial_pos, out);
}